// Round 1
// baseline (194.459 us; speedup 1.0000x reference)
//
#include <hip/hip_runtime.h>
#include <hip/hip_bf16.h>
#include <stdint.h>

// GCN layer: out = relu(agg @ W + vf @ B),  agg = masked-mean of gathered rows.
// Fused as one bf16 GEMM: [agg | vf] (N x 512) @ [W ; B]^T-staged (512 x 256).

#define N_V   50000
#define KNB   16
#define D_F   256
#define H_F   256
#define K2    512            // 2*D
#define NPAD  50048          // N rounded up to 128

typedef __bf16 bf16x8 __attribute__((ext_vector_type(8)));
typedef float  f32x4  __attribute__((ext_vector_type(4)));

static __device__ __forceinline__ unsigned short f2bf(float f) {
    union { float f; unsigned u; } v; v.f = f;
    unsigned u = v.u;
    u += 0x7fffu + ((u >> 16) & 1u);   // round-to-nearest-even
    return (unsigned short)(u >> 16);
}

static __device__ __forceinline__ void load16(const void* g, void* l) {
    __builtin_amdgcn_global_load_lds(
        (__attribute__((address_space(1))) void*)g,
        (__attribute__((address_space(3))) void*)l, 16, 0, 0);
}

// ---------------- kernel 1: W,B -> bf16, transposed to WBt[h][k] ----------
__global__ __launch_bounds__(256) void wb_convert(
    const float* __restrict__ W, const float* __restrict__ Bm,
    unsigned short* __restrict__ WBt) {
    int t = blockIdx.x * 256 + threadIdx.x;    // 0 .. 131071
    int h = t >> 9;                            // /512
    int k = t & 511;
    float v = (k < 256) ? W[(size_t)k * H_F + h]
                        : Bm[(size_t)(k - 256) * H_F + h];
    WBt[t] = f2bf(v);
}

// ---------------- kernel 2: gather + masked mean -> A[n] = [agg | vf] -----
__global__ __launch_bounds__(256) void gather_mean(
    const float* __restrict__ vf, const int* __restrict__ nbr,
    const int* __restrict__ lens, unsigned short* __restrict__ Abuf) {
    int wave = threadIdx.x >> 6;
    int lane = threadIdx.x & 63;
    int n = blockIdx.x * 4 + wave;
    if (n >= NPAD) return;
    unsigned short* arow = Abuf + (size_t)n * K2;
    if (n >= N_V) {                       // zero the pad rows
        ushort4 z = {0, 0, 0, 0};
        ((ushort4*)arow)[lane] = z;
        ((ushort4*)(arow + 256))[lane] = z;
        return;
    }
    int len = lens[n];
    const int* nb = nbr + (size_t)n * KNB;
    float4 acc = make_float4(0.f, 0.f, 0.f, 0.f);
    for (int k = 0; k < len; ++k) {
        int j = __builtin_amdgcn_readfirstlane(nb[k]);  // wave-uniform
        const float4 v = ((const float4*)(vf + (size_t)j * D_F))[lane];
        acc.x += v.x; acc.y += v.y; acc.z += v.z; acc.w += v.w;
    }
    float inv = 1.0f / (float)(len > 0 ? len : 1);
    ushort4 o;
    o.x = f2bf(acc.x * inv); o.y = f2bf(acc.y * inv);
    o.z = f2bf(acc.z * inv); o.w = f2bf(acc.w * inv);
    ((ushort4*)arow)[lane] = o;
    const float4 v = ((const float4*)(vf + (size_t)n * D_F))[lane];
    ushort4 o2;
    o2.x = f2bf(v.x); o2.y = f2bf(v.y); o2.z = f2bf(v.z); o2.w = f2bf(v.w);
    ((ushort4*)(arow + 256))[lane] = o2;
}

// ---------------- kernel 3: bf16 GEMM 128x128 tile + ReLU -----------------
// A[NPAD][512] bf16 row-major, WBt[256][512] bf16 row-major (n-major).
// XOR-swizzle ((row&3)<<4) applied both-sides (pre-swizzled global source,
// linear global_load_lds dest, swizzled ds_read) per rule #21.
__global__ __launch_bounds__(256) void gemm_relu(
    const unsigned short* __restrict__ Abuf,
    const unsigned short* __restrict__ WBt,
    float* __restrict__ out) {
    __shared__ char Alds[8192];   // [128 m][32 k] bf16, swizzled
    __shared__ char Blds[8192];   // [128 n][32 k] bf16, swizzled
    const int bn = blockIdx.x * 128;
    const int bm = blockIdx.y * 128;
    const int tid  = threadIdx.x;
    const int wave = tid >> 6, lane = tid & 63;
    const int wm = wave >> 1, wn = wave & 1;

    f32x4 acc[4][4];
    const f32x4 fzero = {0.f, 0.f, 0.f, 0.f};
#pragma unroll
    for (int i = 0; i < 4; ++i)
#pragma unroll
        for (int j = 0; j < 4; ++j) acc[i][j] = fzero;

    const char* Ab = (const char*)(Abuf + (size_t)bm * K2);
    const char* Bb = (const char*)(WBt + (size_t)bn * K2);

    for (int k0 = 0; k0 < K2; k0 += 32) {
        __syncthreads();
#pragma unroll
        for (int i = 0; i < 2; ++i) {
            unsigned P = i * 4096 + tid * 16;            // physical byte (linear)
            unsigned L = P ^ (((P >> 6) & 3u) << 4);     // logical row/col
            unsigned row = L >> 6;
            unsigned colb = L & 63u;
            const char* ga = Ab + (size_t)row * (K2 * 2) + k0 * 2 + colb;
            const char* gb = Bb + (size_t)row * (K2 * 2) + k0 * 2 + colb;
            char* la = Alds + i * 4096 + wave * 1024;    // wave-uniform base
            char* lb = Blds + i * 4096 + wave * 1024;
            load16(ga, la);
            load16(gb, lb);
        }
        __syncthreads();

        bf16x8 af[4], bfr[4];
#pragma unroll
        for (int mf = 0; mf < 4; ++mf) {
            unsigned r = wm * 64 + mf * 16 + (lane & 15);
            unsigned L = r * 64 + ((lane >> 4) << 4);
            unsigned P = L ^ (((L >> 6) & 3u) << 4);
            af[mf] = *(const bf16x8*)(Alds + P);
        }
#pragma unroll
        for (int nf = 0; nf < 4; ++nf) {
            unsigned r = wn * 64 + nf * 16 + (lane & 15);
            unsigned L = r * 64 + ((lane >> 4) << 4);
            unsigned P = L ^ (((L >> 6) & 3u) << 4);
            bfr[nf] = *(const bf16x8*)(Blds + P);
        }
#pragma unroll
        for (int mf = 0; mf < 4; ++mf)
#pragma unroll
            for (int nf = 0; nf < 4; ++nf)
                acc[mf][nf] = __builtin_amdgcn_mfma_f32_16x16x32_bf16(
                    af[mf], bfr[nf], acc[mf][nf], 0, 0, 0);
    }

    // epilogue: relu + store, guard rows >= N_V
#pragma unroll
    for (int mf = 0; mf < 4; ++mf) {
        int row0 = bm + wm * 64 + mf * 16 + ((lane >> 4) << 2);
#pragma unroll
        for (int nf = 0; nf < 4; ++nf) {
            int col = bn + wn * 64 + nf * 16 + (lane & 15);
            f32x4 v = acc[mf][nf];
#pragma unroll
            for (int i = 0; i < 4; ++i) {
                int row = row0 + i;
                if (row < N_V)
                    out[(size_t)row * H_F + col] = fmaxf(v[i], 0.0f);
            }
        }
    }
}

extern "C" void kernel_launch(void* const* d_in, const int* in_sizes, int n_in,
                              void* d_out, int out_size, void* d_ws, size_t ws_size,
                              hipStream_t stream) {
    const float* vf   = (const float*)d_in[0];
    const int*   nbr  = (const int*)d_in[1];
    const int*   lens = (const int*)d_in[2];
    const float* W    = (const float*)d_in[3];
    const float* Bm   = (const float*)d_in[4];
    float* out = (float*)d_out;

    unsigned short* Abuf = (unsigned short*)d_ws;                         // NPAD*512 bf16
    unsigned short* WBt  = (unsigned short*)((char*)d_ws +
                             (size_t)NPAD * K2 * sizeof(unsigned short)); // 256*512 bf16

    hipLaunchKernelGGL(wb_convert, dim3(512), dim3(256), 0, stream, W, Bm, WBt);
    hipLaunchKernelGGL(gather_mean, dim3(NPAD / 4), dim3(256), 0, stream,
                       vf, nbr, lens, Abuf);
    hipLaunchKernelGGL(gemm_relu, dim3(2, NPAD / 128), dim3(256), 0, stream,
                       Abuf, WBt, out);
}

// Round 2
// 167.332 us; speedup vs baseline: 1.1621x; 1.1621x over previous
//
#include <hip/hip_runtime.h>
#include <stdint.h>

// GCN layer: out = relu(agg @ W + vf @ B),  agg = masked-mean of gathered rows.
// Pipeline: vf->bf16 (vfb), W/B->bf16 transposed (WBt), bf16 gather-mean (aggb),
// then one bf16 GEMM with A = [aggb | vfb] (k<256 / k>=256) and fused ReLU.

#define N_V   50000
#define KNB   16
#define D_F   256
#define H_F   256
#define K2    512
#define NPAD  50048          // N rounded up to 128

typedef __bf16 bf16x8 __attribute__((ext_vector_type(8)));
typedef float  f32x4  __attribute__((ext_vector_type(4)));
typedef unsigned short ushort8 __attribute__((ext_vector_type(8)));

static __device__ __forceinline__ unsigned short f2bf(float f) {
    union { float f; unsigned u; } v; v.f = f;
    unsigned u = v.u;
    u += 0x7fffu + ((u >> 16) & 1u);   // round-to-nearest-even
    return (unsigned short)(u >> 16);
}
static __device__ __forceinline__ float bf2f(unsigned short u) {
    union { unsigned u; float f; } v; v.u = ((unsigned)u) << 16; return v.f;
}
static __device__ __forceinline__ void load16(const void* g, void* l) {
    __builtin_amdgcn_global_load_lds(
        (__attribute__((address_space(1))) void*)g,
        (__attribute__((address_space(3))) void*)l, 16, 0, 0);
}

// ---------------- kernel 1: vf fp32 -> vfb bf16 (rows >= N_V zeroed) ------
__global__ __launch_bounds__(256) void vf_convert(
    const float* __restrict__ vf, unsigned short* __restrict__ vfb) {
    const int total = NPAD * (D_F / 8);            // 16-B chunks
    for (int c = blockIdx.x * 256 + threadIdx.x; c < total; c += gridDim.x * 256) {
        int n = c >> 5;                            // 32 chunks per 256-elem row
        int off = (c & 31) * 8;
        ushort8 o;
        if (n < N_V) {
            const float4 a = *(const float4*)(vf + (size_t)n * D_F + off);
            const float4 b = *(const float4*)(vf + (size_t)n * D_F + off + 4);
            o[0]=f2bf(a.x); o[1]=f2bf(a.y); o[2]=f2bf(a.z); o[3]=f2bf(a.w);
            o[4]=f2bf(b.x); o[5]=f2bf(b.y); o[6]=f2bf(b.z); o[7]=f2bf(b.w);
        } else {
            o = (ushort8)(0);
        }
        *(ushort8*)(vfb + (size_t)n * D_F + off) = o;
    }
}

// ---------------- kernel 2: W,B -> bf16 transposed WBt[h][k], coalesced ---
__global__ __launch_bounds__(256) void wbt_convert(
    const float* __restrict__ W, const float* __restrict__ Bm,
    unsigned short* __restrict__ WBt) {
    __shared__ unsigned short t[32][34];
    const int k0 = blockIdx.x * 32;                // 0..480
    const int h0 = blockIdx.y * 32;                // 0..224
    const int tid = threadIdx.x;
    {   // load: coalesced fp32 reads, row-major in W/B
        int r  = tid >> 3;                         // k row 0..31
        int c4 = (tid & 7) * 4;                    // h col 0..28
        int kg = k0 + r;
        const float* src = (kg < 256) ? (W  + (size_t)kg * H_F + h0 + c4)
                                      : (Bm + (size_t)(kg - 256) * H_F + h0 + c4);
        float4 v = *(const float4*)src;
        t[r][c4 + 0] = f2bf(v.x); t[r][c4 + 1] = f2bf(v.y);
        t[r][c4 + 2] = f2bf(v.z); t[r][c4 + 3] = f2bf(v.w);
    }
    __syncthreads();
    {   // store: coalesced bf16 writes, row-major in WBt[h][k]
        int hh  = tid >> 3;                        // h row 0..31
        int kk4 = (tid & 7) * 4;                   // k col 0..28
        ushort4 o;
        o.x = t[kk4 + 0][hh]; o.y = t[kk4 + 1][hh];
        o.z = t[kk4 + 2][hh]; o.w = t[kk4 + 3][hh];
        *(ushort4*)(WBt + (size_t)(h0 + hh) * K2 + k0 + kk4) = o;
    }
}

// ---------------- kernel 3: bf16 gather + masked mean ---------------------
__global__ __launch_bounds__(256) void gather_mean(
    const unsigned short* __restrict__ vfb, const int* __restrict__ nbr,
    const int* __restrict__ lens, unsigned short* __restrict__ aggb) {
    const int wave = threadIdx.x >> 6;
    const int lane = threadIdx.x & 63;
    const int n = blockIdx.x * 4 + wave;
    if (n >= NPAD) return;
    unsigned short* arow = aggb + (size_t)n * D_F;
    if (n >= N_V) {                                // zero pad rows
        ushort4 z = {0, 0, 0, 0};
        *(ushort4*)(arow + lane * 4) = z;
        return;
    }
    const int len = lens[n];
    const int idx = nbr[(size_t)n * KNB + (lane & 15)];
    f32x4 acc = {0.f, 0.f, 0.f, 0.f};
#define ROW_(j) (*(const ushort4*)(vfb + (size_t)(j) * D_F + lane * 4))
#define ACC_(v) { acc[0] += bf2f(v.x); acc[1] += bf2f(v.y); \
                  acc[2] += bf2f(v.z); acc[3] += bf2f(v.w); }
    int k = 0;
    for (; k + 4 <= len; k += 4) {
        int j0 = __shfl(idx, k),     j1 = __shfl(idx, k + 1);
        int j2 = __shfl(idx, k + 2), j3 = __shfl(idx, k + 3);
        ushort4 v0 = ROW_(j0), v1 = ROW_(j1), v2 = ROW_(j2), v3 = ROW_(j3);
        ACC_(v0); ACC_(v1); ACC_(v2); ACC_(v3);
    }
    for (; k < len; ++k) {
        int j = __shfl(idx, k);
        ushort4 v = ROW_(j);
        ACC_(v);
    }
#undef ROW_
#undef ACC_
    const float inv = 1.0f / (float)(len > 0 ? len : 1);
    ushort4 o;
    o.x = f2bf(acc[0] * inv); o.y = f2bf(acc[1] * inv);
    o.z = f2bf(acc[2] * inv); o.w = f2bf(acc[3] * inv);
    *(ushort4*)(arow + lane * 4) = o;
}

// ---------------- kernel 4: bf16 GEMM 128x256 + ReLU, 2-phase pipeline ----
// A rows: k<256 from aggb, k>=256 from vfb (both [NPAD][256] bf16).
// B: WBt[256 n][512 k] bf16. XOR-swizzle ((row&3)<<4) both-sides.
__global__ __launch_bounds__(512) void gemm_relu(
    const unsigned short* __restrict__ aggb,
    const unsigned short* __restrict__ vfb,
    const unsigned short* __restrict__ WBt,
    float* __restrict__ out) {
    __shared__ char Alds[2][8192];    // [128 m][32 k] bf16, swizzled
    __shared__ char Blds[2][16384];   // [256 n][32 k] bf16, swizzled
    const int bm = blockIdx.x * 128;
    const int tid  = threadIdx.x;
    const int wave = tid >> 6, lane = tid & 63;
    const int wm = wave >> 2, wn = wave & 3;      // 2 x 4 waves of 64x64

    f32x4 acc[4][4];
    const f32x4 fzero = {0.f, 0.f, 0.f, 0.f};
#pragma unroll
    for (int i = 0; i < 4; ++i)
#pragma unroll
        for (int j = 0; j < 4; ++j) acc[i][j] = fzero;

    auto stage = [&](int buf, int t) {
        const int k0 = t * 32;
        {   // A: 8 KB, one 16-B load/thread
            unsigned P = tid * 16u;
            unsigned L = P ^ (((P >> 6) & 3u) << 4);
            unsigned row = L >> 6, colb = L & 63u;
            const char* src = (k0 < 256)
                ? (const char*)aggb + (size_t)(bm + row) * 512 + k0 * 2 + colb
                : (const char*)vfb  + (size_t)(bm + row) * 512 + (k0 - 256) * 2 + colb;
            load16(src, Alds[buf] + wave * 1024);
        }
#pragma unroll
        for (int i = 0; i < 2; ++i) {   // B: 16 KB, two 16-B loads/thread
            unsigned P = i * 8192u + tid * 16u;
            unsigned L = P ^ (((P >> 6) & 3u) << 4);
            unsigned row = L >> 6, colb = L & 63u;      // n = 0..255
            const char* src = (const char*)WBt + (size_t)row * 1024 + k0 * 2 + colb;
            load16(src, Blds[buf] + i * 8192 + wave * 1024);
        }
    };

    stage(0, 0);
    __syncthreads();                   // drains vmcnt(0): buf0 ready
    int cur = 0;
    for (int t = 0; t < 16; ++t) {
        if (t < 15) stage(cur ^ 1, t + 1);   // in flight across compute
        bf16x8 af[4], bfr[4];
#pragma unroll
        for (int mf = 0; mf < 4; ++mf) {
            unsigned r = wm * 64 + mf * 16 + (lane & 15);
            unsigned L = r * 64 + ((lane >> 4) << 4);
            unsigned P = L ^ (((L >> 6) & 3u) << 4);
            af[mf] = *(const bf16x8*)(Alds[cur] + P);
        }
#pragma unroll
        for (int nf = 0; nf < 4; ++nf) {
            unsigned r = wn * 64 + nf * 16 + (lane & 15);
            unsigned L = r * 64 + ((lane >> 4) << 4);
            unsigned P = L ^ (((L >> 6) & 3u) << 4);
            bfr[nf] = *(const bf16x8*)(Blds[cur] + P);
        }
#pragma unroll
        for (int mf = 0; mf < 4; ++mf)
#pragma unroll
            for (int nf = 0; nf < 4; ++nf)
                acc[mf][nf] = __builtin_amdgcn_mfma_f32_16x16x32_bf16(
                    af[mf], bfr[nf], acc[mf][nf], 0, 0, 0);
        __syncthreads();               // drains vmcnt(0): next buf ready
        cur ^= 1;
    }

    // epilogue: relu + store, guard rows >= N_V
#pragma unroll
    for (int mf = 0; mf < 4; ++mf) {
        int row0 = bm + wm * 64 + mf * 16 + ((lane >> 4) << 2);
#pragma unroll
        for (int nf = 0; nf < 4; ++nf) {
            int col = wn * 64 + nf * 16 + (lane & 15);
            f32x4 v = acc[mf][nf];
#pragma unroll
            for (int i = 0; i < 4; ++i) {
                int row = row0 + i;
                if (row < N_V)
                    out[(size_t)row * H_F + col] = fmaxf(v[i], 0.0f);
            }
        }
    }
}

extern "C" void kernel_launch(void* const* d_in, const int* in_sizes, int n_in,
                              void* d_out, int out_size, void* d_ws, size_t ws_size,
                              hipStream_t stream) {
    const float* vf   = (const float*)d_in[0];
    const int*   nbr  = (const int*)d_in[1];
    const int*   lens = (const int*)d_in[2];
    const float* W    = (const float*)d_in[3];
    const float* Bm   = (const float*)d_in[4];
    float* out = (float*)d_out;

    unsigned short* aggb = (unsigned short*)d_ws;                          // NPAD*256 bf16
    unsigned short* vfb  = aggb + (size_t)NPAD * D_F;                      // NPAD*256 bf16
    unsigned short* WBt  = vfb + (size_t)NPAD * D_F;                       // 256*512 bf16

    hipLaunchKernelGGL(vf_convert, dim3(2048), dim3(256), 0, stream, vf, vfb);
    hipLaunchKernelGGL(wbt_convert, dim3(16, 8), dim3(256), 0, stream, W, Bm, WBt);
    hipLaunchKernelGGL(gather_mean, dim3(NPAD / 4), dim3(256), 0, stream,
                       vfb, nbr, lens, aggb);
    hipLaunchKernelGGL(gemm_relu, dim3(NPAD / 128), dim3(512), 0, stream,
                       aggb, vfb, WBt, out);
}